// Round 8
// baseline (223.989 us; speedup 1.0000x reference)
//
#include <hip/hip_runtime.h>
#include <stdint.h>

#define B_ 8
#define K_ 8
#define N_ 128
#define D_ 256
#define H_ 128
#define NNEG_ 64

typedef unsigned long long u64;

// ---------------------------------------------------------------------------
// u64 wave shuffles + bitonic helpers
// ---------------------------------------------------------------------------
__device__ __forceinline__ u64 shfl_xor_u64(u64 v, int m) {
    int lo = __shfl_xor((int)(unsigned)v, m, 64);
    int hi = __shfl_xor((int)(unsigned)(v >> 32), m, 64);
    return ((u64)(unsigned)hi << 32) | (unsigned)lo;
}
__device__ __forceinline__ u64 bitonic_merge64(u64 m, int lane) {
#pragma unroll
    for (int j = 32; j > 0; j >>= 1) {
        u64 o = shfl_xor_u64(m, j);
        bool keepMin = ((lane & j) == 0);
        bool lt = m < o;
        m = (keepMin == lt) ? m : o;
    }
    return m;
}
__device__ __forceinline__ unsigned sortable(float f) {
    unsigned u = __float_as_uint(f);
    return (u & 0x80000000u) ? ~u : (u | 0x80000000u);
}
__device__ __forceinline__ float unsortable(unsigned u) {
    return __uint_as_float((u & 0x80000000u) ? (u & 0x7FFFFFFFu) : ~u);
}
// wave0-only: sort cand[0..127] ascending; 2 elems/lane
__device__ __forceinline__ void sort128_wave0(u64* cand, int cc, int lane) {
    u64 v0 = (lane < cc) ? cand[lane] : ~0ull;
    u64 v1 = (64 + lane < cc) ? cand[64 + lane] : ~0ull;
#pragma unroll
    for (int k = 2; k <= 64; k <<= 1) {
        bool d0 = ((lane & k) == 0);
        bool d1 = (k == 64) ? false : d0;
#pragma unroll
        for (int j = k >> 1; j > 0; j >>= 1) {
            u64 o0 = shfl_xor_u64(v0, j);
            bool km0 = (((lane & j) == 0) == d0);
            v0 = (km0 == (v0 < o0)) ? v0 : o0;
            u64 o1 = shfl_xor_u64(v1, j);
            bool km1 = (((lane & j) == 0) == d1);
            v1 = (km1 == (v1 < o1)) ? v1 : o1;
        }
    }
    if (v0 > v1) { u64 tmp = v0; v0 = v1; v1 = tmp; }
#pragma unroll
    for (int j = 32; j > 0; j >>= 1) {
        bool km = ((lane & j) == 0);
        u64 o0 = shfl_xor_u64(v0, j);
        v0 = (km == (v0 < o0)) ? v0 : o0;
        u64 o1 = shfl_xor_u64(v1, j);
        v1 = (km == (v1 < o1)) ? v1 : o1;
    }
    cand[lane] = v0; cand[64 + lane] = v1;
}

// ---------------------------------------------------------------------------
// g1: 4 GEMMs + is_target.  blocks 0..223 = 128x128 tiles (8x8/thread,
// K-quad b128 A-frags, ty-strided rows for bank-conflict-free reads);
// blocks 224..227 = is_target.
// ---------------------------------------------------------------------------
__global__ __launch_bounds__(256) void g1_gemm(
    const float* __restrict__ pos, const float* __restrict__ neg,
    const float* __restrict__ Wu1, const float* __restrict__ Wp1,
    const int* __restrict__ pos_classes, const int* __restrict__ target_class,
    float* __restrict__ HU0, float* __restrict__ HU1n,
    float* __restrict__ HP0, float* __restrict__ HP1,
    float* __restrict__ outp) {
    int bid = blockIdx.x;
    int t = threadIdx.x;
    if (bid >= 224) {
        int base = (bid - 224) * 2048 + t * 8;
#pragma unroll
        for (int q = 0; q < 8; ++q) {
            int idx = base + q;
            outp[64 + idx] = (pos_classes[idx] == target_class[idx >> 10]) ? 1.0f : 0.0f;
        }
        return;
    }
    const float* A; const float* W; float* OUT; int rb;
    if (bid < 64)       { A = pos; W = Wu1;           OUT = HU0;  rb = bid * 128; }
    else if (bid < 96)  { A = neg; W = Wu1 + D_ * H_; OUT = HU1n; rb = (bid - 64) * 128; }
    else if (bid < 160) { A = pos; W = Wp1;           OUT = HP0;  rb = (bid - 96) * 128; }
    else                { A = pos; W = Wp1 + D_ * H_; OUT = HP1;  rb = (bid - 160) * 128; }

    __shared__ float As[128][20];   // stride 20: 80B rows (16B-aligned), banks spread
    __shared__ float Bs[16][132];   // stride 132: 528B rows (16B-aligned)
    int tx = t & 15, ty = t >> 4;   // tx: col-group (8 cols), ty: row base (rows ty+16i)
    float acc[8][8];
#pragma unroll
    for (int i = 0; i < 8; ++i)
#pragma unroll
        for (int j = 0; j < 8; ++j) acc[i][j] = 0.f;

    for (int k0 = 0; k0 < D_; k0 += 16) {
#pragma unroll
        for (int q = 0; q < 2; ++q) {
            int f = q * 256 + t;
            int row = f >> 2, kq = (f & 3) * 4;
            *(float4*)&As[row][kq] =
                *(const float4*)&A[(size_t)(rb + row) * D_ + k0 + kq];
            int kr = f >> 5, hc = (f & 31) * 4;
            *(float4*)&Bs[kr][hc] =
                *(const float4*)&W[(size_t)(k0 + kr) * H_ + hc];
        }
        __syncthreads();
#pragma unroll
        for (int kq = 0; kq < 16; kq += 4) {
            float4 af[8];
#pragma unroll
            for (int i = 0; i < 8; ++i)
                af[i] = *(const float4*)&As[ty + 16 * i][kq];
            float4 b0[4], b1[4];
#pragma unroll
            for (int j = 0; j < 4; ++j) {
                b0[j] = *(const float4*)&Bs[kq + j][tx * 8];
                b1[j] = *(const float4*)&Bs[kq + j][tx * 8 + 4];
            }
#pragma unroll
            for (int j = 0; j < 4; ++j) {
#pragma unroll
                for (int i = 0; i < 8; ++i) {
                    float a = (&af[i].x)[j];
                    acc[i][0] += a * b0[j].x;
                    acc[i][1] += a * b0[j].y;
                    acc[i][2] += a * b0[j].z;
                    acc[i][3] += a * b0[j].w;
                    acc[i][4] += a * b1[j].x;
                    acc[i][5] += a * b1[j].y;
                    acc[i][6] += a * b1[j].z;
                    acc[i][7] += a * b1[j].w;
                }
            }
        }
        __syncthreads();
    }
#pragma unroll
    for (int i = 0; i < 8; ++i) {
        int row = rb + ty + 16 * i;
        float4 o0 = {acc[i][0], acc[i][1], acc[i][2], acc[i][3]};
        float4 o1 = {acc[i][4], acc[i][5], acc[i][6], acc[i][7]};
        *(float4*)&OUT[(size_t)row * H_ + tx * 8] = o0;
        *(float4*)&OUT[(size_t)row * H_ + tx * 8 + 4] = o1;
    }
}

// ---------------------------------------------------------------------------
// g2: blocks 0..255 = ue (t0), blocks 256..511 = score0 (sc0 = dot + bp2).
// Inner loop vectorized over h (4/iter, all-b128 LDS reads); m-assignment
// strided (tm + 8i) for conflict-free Ls reads; pads 132 keep 16B alignment.
// ---------------------------------------------------------------------------
__global__ __launch_bounds__(256) void g2_ue_sc0(
    const float* __restrict__ HU0, const float* __restrict__ HU1n,
    const float* __restrict__ bu1, const float* __restrict__ Wu2,
    const float* __restrict__ bu2v,
    const float* __restrict__ HP0, const float* __restrict__ HP1,
    const float* __restrict__ bp1, const float* __restrict__ Wp2,
    const float* __restrict__ bp2,
    float* __restrict__ t0, float* __restrict__ sc0) {
    __shared__ float Ls[32][132];
    __shared__ float Rs[64][132];
    __shared__ float wsv[128];
    __shared__ float red[32][33];

    int bid = blockIdx.x;
    int t = threadIdx.x;
    bool is_ue = bid < 256;

    if (is_ue) {
        int bk = bid >> 2, mt = bid & 3;
        for (int i = t; i < 64 * 128; i += 256) {
            int n = i >> 7, h = i & 127;
            Rs[n][h] = HU1n[(size_t)(bk * NNEG_ + n) * H_ + h];
        }
        for (int i = t; i < 32 * 128; i += 256) {
            int m = i >> 7, h = i & 127;
            Ls[m][h] = HU0[(size_t)(bk * N_ + mt * 32 + m) * H_ + h] + bu1[h];
        }
        if (t < 128) wsv[t] = Wu2[t];
    } else {
        int bid2 = bid - 256;
        int b = bid2 >> 3, m0t = (bid2 >> 1) & 3, m1t = bid2 & 1;
        const float* Lg = HP0 + (size_t)b * 2 * N_ * H_ + m0t * 32 * H_;
        const float* Rg = HP1 + (size_t)b * 2 * N_ * H_ + N_ * H_ + m1t * 64 * H_;
        for (int i = t; i < 64 * 128; i += 256) {
            int n = i >> 7, h = i & 127;
            Rs[n][h] = Rg[(size_t)n * H_ + h];
        }
        for (int i = t; i < 32 * 128; i += 256) {
            int m = i >> 7, h = i & 127;
            Ls[m][h] = Lg[(size_t)m * H_ + h] + bp1[h];
        }
        if (t < 128) wsv[t] = Wp2[t];
    }
    __syncthreads();

    int tm = t & 7, tn = t >> 3;   // m = tm + 8*i (strided), n = tn*2 + j
    float a00 = 0.f, a01 = 0.f, a10 = 0.f, a11 = 0.f;
    float a20 = 0.f, a21 = 0.f, a30 = 0.f, a31 = 0.f;
#pragma unroll 2
    for (int h = 0; h < 128; h += 4) {
        float4 wv = *(const float4*)&wsv[h];
        float4 r0 = *(const float4*)&Rs[tn * 2][h];
        float4 r1 = *(const float4*)&Rs[tn * 2 + 1][h];
        float4 l0 = *(const float4*)&Ls[tm][h];
        float4 l1 = *(const float4*)&Ls[tm + 8][h];
        float4 l2 = *(const float4*)&Ls[tm + 16][h];
        float4 l3 = *(const float4*)&Ls[tm + 24][h];
#pragma unroll
        for (int c = 0; c < 4; ++c) {
            float w = (&wv.x)[c];
            float b0 = (&r0.x)[c], b1 = (&r1.x)[c];
            float x0 = (&l0.x)[c], x1 = (&l1.x)[c];
            float x2 = (&l2.x)[c], x3 = (&l3.x)[c];
            float v;
            v = x0 + b0; v = v > 0.f ? v : 0.f; a00 += v * w;
            v = x0 + b1; v = v > 0.f ? v : 0.f; a01 += v * w;
            v = x1 + b0; v = v > 0.f ? v : 0.f; a10 += v * w;
            v = x1 + b1; v = v > 0.f ? v : 0.f; a11 += v * w;
            v = x2 + b0; v = v > 0.f ? v : 0.f; a20 += v * w;
            v = x2 + b1; v = v > 0.f ? v : 0.f; a21 += v * w;
            v = x3 + b0; v = v > 0.f ? v : 0.f; a30 += v * w;
            v = x3 + b1; v = v > 0.f ? v : 0.f; a31 += v * w;
        }
    }

    if (is_ue) {
        int bk = bid >> 2, mt = bid & 3;
        red[tm + 0][tn] = a00 + a01;
        red[tm + 8][tn] = a10 + a11;
        red[tm + 16][tn] = a20 + a21;
        red[tm + 24][tn] = a30 + a31;
        __syncthreads();
        if (t < 32) {
            float s = 0.f;
            for (int q = 0; q < 32; ++q) s += red[t][q];
            t0[bk * N_ + mt * 32 + t] = s * (1.0f / NNEG_) + bu2v[0];
        }
    } else {
        int bid2 = bid - 256;
        int b = bid2 >> 3, m0t = (bid2 >> 1) & 3, m1t = bid2 & 1;
        float bp2v = bp2[0];
        float* orow = sc0 + (size_t)b * 16384;
        float accs[4][2] = {{a00, a01}, {a10, a11}, {a20, a21}, {a30, a31}};
#pragma unroll
        for (int i = 0; i < 4; ++i) {
            int m0 = m0t * 32 + tm + 8 * i;
#pragma unroll
            for (int j = 0; j < 2; ++j) {
                int m1 = m1t * 64 + tn * 2 + j;
                orow[m0 * 128 + m1] = accs[i][j] + bp2v;
            }
        }
    }
}

// ---------------------------------------------------------------------------
// g3: level-0 top-64 per row.  32 blocks x 1024 (16 waves).
// 2-bit descent select: 16 iterations, ONE barrier each.
// ---------------------------------------------------------------------------
__global__ __launch_bounds__(1024) void g3_top0(const float* __restrict__ sc0,
                                                const float* __restrict__ t0,
                                                float* __restrict__ tA,
                                                int* __restrict__ pA) {
    int r = blockIdx.x;
    int t = threadIdx.x, lane = t & 63;
    __shared__ float tt[256];
    __shared__ unsigned cnt[16][2];
    __shared__ unsigned ccnt;
    __shared__ u64 cand[128];
    if (t < 256) tt[t] = t0[r * 256 + t];
    if (t < 32) cnt[t >> 1][t & 1] = 0u;
    if (t == 0) ccnt = 0u;
    __syncthreads();
    const float* row = sc0 + (size_t)r * 16384;
    unsigned sv[16];
#pragma unroll
    for (int j = 0; j < 16; ++j) {
        int idx = j * 1024 + t;
        float v = (tt[idx >> 7] + tt[128 + (idx & 127)]) - row[idx];
        sv[j] = sortable(v);
    }
    unsigned T = 0u;
#pragma unroll
    for (int it = 0; it < 16; ++it) {
        int p = 30 - 2 * it;
        unsigned C1 = T | (1u << p), C2 = T | (2u << p), C3 = T | (3u << p);
        unsigned c13 = 0u, c2 = 0u;
#pragma unroll
        for (int j = 0; j < 16; ++j) {
            c13 += (sv[j] < C1) ? 1u : 0u;
            c13 += (sv[j] < C3) ? 0x10000u : 0u;
            c2 += (sv[j] < C2) ? 1u : 0u;
        }
#pragma unroll
        for (int off = 32; off > 0; off >>= 1) {
            c13 += (unsigned)__shfl_xor((int)c13, off, 64);
            c2 += (unsigned)__shfl_xor((int)c2, off, 64);
        }
        if (lane == 0) { atomicAdd(&cnt[it][0], c13); atomicAdd(&cnt[it][1], c2); }
        __syncthreads();
        unsigned t13 = cnt[it][0], t2v = cnt[it][1];
        unsigned t1 = t13 & 0xFFFFu, t3 = t13 >> 16;
        unsigned k = (t3 < 64u) ? 3u : (t2v < 64u) ? 2u : (t1 < 64u) ? 1u : 0u;
        T |= (k << p);
    }
#pragma unroll
    for (int j = 0; j < 16; ++j) {
        if (sv[j] <= T) {
            unsigned pos = atomicAdd(&ccnt, 1u);
            if (pos < 128u) {
                int idx = j * 1024 + t;
                cand[pos] = ((u64)sv[j] << 32) | (unsigned)idx;
            }
        }
    }
    __syncthreads();
    if (t < 64) {
        int cc = (int)(ccnt < 128u ? ccnt : 128u);
        sort128_wave0(cand, cc, lane);
        u64 kk = cand[lane];
        int idx = (int)(kk & 0xFFFFFFFFull);
        tA[r * 64 + lane] = unsortable((unsigned)(kk >> 32));
        pA[r * 64 + lane] = ((idx >> 7) << 8) | (idx & 127);
    }
}

// ---------------------------------------------------------------------------
// g4a: level-1 scoring + per-half top-64.  32 blocks (unit u, n-half) x 256.
// ---------------------------------------------------------------------------
__global__ __launch_bounds__(256) void g4a_s1(
    const float* __restrict__ HP0, const float* __restrict__ HP1,
    const float* __restrict__ tA, const int* __restrict__ pA,
    const float* __restrict__ bp1, const float* __restrict__ Wp2,
    const float* __restrict__ bp2, u64* __restrict__ g4top) {
    int bid = blockIdx.x;
    int u = bid >> 1, half = bid & 1;
    int t = threadIdx.x, lane = t & 63, w = t >> 6;
    __shared__ float LsT[128][68];
    __shared__ float RsT[128][36];
    __shared__ float taL[64], taR[64];
    __shared__ int paL[64], paR[64];
    __shared__ float wsv[128];
    __shared__ unsigned cnt[16][2];
    __shared__ unsigned ccnt;
    __shared__ u64 cand[128];
    if (t < 64) { taL[t] = tA[(2 * u) * 64 + t]; paL[t] = pA[(2 * u) * 64 + t]; }
    else if (t < 128) { int e = t - 64; taR[e] = tA[(2 * u + 1) * 64 + e]; paR[e] = pA[(2 * u + 1) * 64 + e]; }
    if (t < 128) wsv[t] = Wp2[t];
    if (t < 32) cnt[t >> 1][t & 1] = 0u;
    if (t == 0) ccnt = 0u;
    float bp2v = bp2[0];
    __syncthreads();
    for (int i = t; i < 64 * 128; i += 256) {
        int m = i >> 7, h = i & 127;
        int pk = paL[m]; int a0 = pk >> 8, a1 = pk & 255;
        float s = HP0[(size_t)(4 * u) * 16384 + a0 * 128 + h]
                + HP0[(size_t)(4 * u + 1) * 16384 + a1 * 128 + h];
        LsT[h][m] = s * 0.5f + bp1[h];
    }
    for (int i = t; i < 32 * 128; i += 256) {
        int n = i >> 7, h = i & 127;
        int ng = half * 32 + n;
        int pk = paR[ng]; int c0 = pk >> 8, c1 = pk & 255;
        float s = HP1[(size_t)(4 * u + 2) * 16384 + c0 * 128 + h]
                + HP1[(size_t)(4 * u + 3) * 16384 + c1 * 128 + h];
        RsT[h][n] = s * 0.5f;
    }
    __syncthreads();
    int qm = w * 4 + (lane >> 4);
    int qn = lane & 15;
    float acc[4][2];
#pragma unroll
    for (int i = 0; i < 4; ++i) { acc[i][0] = 0.f; acc[i][1] = 0.f; }
#pragma unroll 2
    for (int h = 0; h < 128; ++h) {
        float4 lv = *(const float4*)&LsT[h][qm * 4];
        float2 rv = *(const float2*)&RsT[h][qn * 2];
        float wv = wsv[h];
        float v;
        v = lv.x + rv.x; v = v > 0.f ? v : 0.f; acc[0][0] += v * wv;
        v = lv.x + rv.y; v = v > 0.f ? v : 0.f; acc[0][1] += v * wv;
        v = lv.y + rv.x; v = v > 0.f ? v : 0.f; acc[1][0] += v * wv;
        v = lv.y + rv.y; v = v > 0.f ? v : 0.f; acc[1][1] += v * wv;
        v = lv.z + rv.x; v = v > 0.f ? v : 0.f; acc[2][0] += v * wv;
        v = lv.z + rv.y; v = v > 0.f ? v : 0.f; acc[2][1] += v * wv;
        v = lv.w + rv.x; v = v > 0.f ? v : 0.f; acc[3][0] += v * wv;
        v = lv.w + rv.y; v = v > 0.f ? v : 0.f; acc[3][1] += v * wv;
    }
    unsigned sv[8];
#pragma unroll
    for (int mi = 0; mi < 4; ++mi) {
#pragma unroll
        for (int nj = 0; nj < 2; ++nj) {
            int m = qm * 4 + mi;
            int ng = half * 32 + qn * 2 + nj;
            float val = (taL[m] + taR[ng]) - (acc[mi][nj] + bp2v);
            sv[mi * 2 + nj] = sortable(val);
        }
    }
    unsigned T = 0u;
#pragma unroll
    for (int it = 0; it < 16; ++it) {
        int p = 30 - 2 * it;
        unsigned C1 = T | (1u << p), C2 = T | (2u << p), C3 = T | (3u << p);
        unsigned c13 = 0u, c2 = 0u;
#pragma unroll
        for (int j = 0; j < 8; ++j) {
            c13 += (sv[j] < C1) ? 1u : 0u;
            c13 += (sv[j] < C3) ? 0x10000u : 0u;
            c2 += (sv[j] < C2) ? 1u : 0u;
        }
#pragma unroll
        for (int off = 32; off > 0; off >>= 1) {
            c13 += (unsigned)__shfl_xor((int)c13, off, 64);
            c2 += (unsigned)__shfl_xor((int)c2, off, 64);
        }
        if (lane == 0) { atomicAdd(&cnt[it][0], c13); atomicAdd(&cnt[it][1], c2); }
        __syncthreads();
        unsigned t13 = cnt[it][0], t2v = cnt[it][1];
        unsigned t1 = t13 & 0xFFFFu, t3 = t13 >> 16;
        unsigned k = (t3 < 64u) ? 3u : (t2v < 64u) ? 2u : (t1 < 64u) ? 1u : 0u;
        T |= (k << p);
    }
#pragma unroll
    for (int j = 0; j < 8; ++j) {
        if (sv[j] <= T) {
            unsigned pos = atomicAdd(&ccnt, 1u);
            if (pos < 128u) {
                int mi = j >> 1, nj = j & 1;
                int idx = (qm * 4 + mi) * 64 + half * 32 + qn * 2 + nj;
                cand[pos] = ((u64)sv[j] << 32) | (unsigned)idx;
            }
        }
    }
    __syncthreads();
    if (w == 0) {
        int cc = (int)(ccnt < 128u ? ccnt : 128u);
        sort128_wave0(cand, cc, lane);
        g4top[(size_t)bid * 64 + lane] = cand[lane];
    }
}

// ---------------------------------------------------------------------------
// g4b: merge half-topks -> level-1 top-64; level-2 scoring (S=4) + argmin; out.
// ---------------------------------------------------------------------------
__global__ __launch_bounds__(256) void g4b_s2(
    const float* __restrict__ HP0, const float* __restrict__ HP1,
    const int* __restrict__ pA, const u64* __restrict__ g4top,
    const float* __restrict__ bp1, const float* __restrict__ Wp2,
    const float* __restrict__ bp2, float* __restrict__ outp) {
    int b = blockIdx.x;
    int t = threadIdx.x, lane = t & 63, w = t >> 6;
    __shared__ float LsT[128][68];
    __shared__ float RsT[128][36];
    __shared__ float tL[64], tR[64];
    __shared__ unsigned subL[64], subR[64];
    __shared__ float wsv[128];
    __shared__ u64 sred[4];
    if (t < 128) wsv[t] = Wp2[t];
    float bp2v = bp2[0];
    if (w < 2) {
        const u64* A = g4top + (size_t)(4 * b + 2 * w) * 64;
        const u64* Bp = g4top + (size_t)(4 * b + 2 * w + 1) * 64;
        u64 x = A[lane], y = Bp[63 - lane];
        u64 m = x < y ? x : y;
        m = bitonic_merge64(m, lane);
        int idx = (int)(m & 0xFFFFFFFFull);
        int p0 = idx >> 6, p1 = idx & 63;
        float val = unsortable((unsigned)(m >> 32));
        int rowL = 4 * b + 2 * w;
        int pkL = pA[rowL * 64 + p0];
        int pkR = pA[(rowL + 1) * 64 + p1];
        unsigned leaves = ((unsigned)pkL << 16) | (unsigned)pkR;
        if (w == 0) { tL[lane] = val; subL[lane] = leaves; }
        else        { tR[lane] = val; subR[lane] = leaves; }
    }
    __syncthreads();
    for (int i = t; i < 64 * 128; i += 256) {
        int m = i >> 7, h = i & 127;
        unsigned s4 = subL[m];
        float s = HP0[(size_t)(8 * b + 0) * 16384 + ((s4 >> 24) & 255u) * 128 + h]
                + HP0[(size_t)(8 * b + 1) * 16384 + ((s4 >> 16) & 255u) * 128 + h]
                + HP0[(size_t)(8 * b + 2) * 16384 + ((s4 >> 8) & 255u) * 128 + h]
                + HP0[(size_t)(8 * b + 3) * 16384 + (s4 & 255u) * 128 + h];
        LsT[h][m] = s * 0.25f + bp1[h];
    }
    u64 best = ~0ull;
    int qm = w * 4 + (lane >> 4);
    int qn = lane & 15;
    for (int half = 0; half < 2; ++half) {
        __syncthreads();
        for (int i = t; i < 32 * 128; i += 256) {
            int n = i >> 7, h = i & 127;
            int ng = half * 32 + n;
            unsigned s4 = subR[ng];
            float s = HP1[(size_t)(8 * b + 4) * 16384 + ((s4 >> 24) & 255u) * 128 + h]
                    + HP1[(size_t)(8 * b + 5) * 16384 + ((s4 >> 16) & 255u) * 128 + h]
                    + HP1[(size_t)(8 * b + 6) * 16384 + ((s4 >> 8) & 255u) * 128 + h]
                    + HP1[(size_t)(8 * b + 7) * 16384 + (s4 & 255u) * 128 + h];
            RsT[h][n] = s * 0.25f;
        }
        __syncthreads();
        float acc[4][2];
#pragma unroll
        for (int i = 0; i < 4; ++i) { acc[i][0] = 0.f; acc[i][1] = 0.f; }
#pragma unroll 2
        for (int h = 0; h < 128; ++h) {
            float4 lv = *(const float4*)&LsT[h][qm * 4];
            float2 rv = *(const float2*)&RsT[h][qn * 2];
            float wv = wsv[h];
            float v;
            v = lv.x + rv.x; v = v > 0.f ? v : 0.f; acc[0][0] += v * wv;
            v = lv.x + rv.y; v = v > 0.f ? v : 0.f; acc[0][1] += v * wv;
            v = lv.y + rv.x; v = v > 0.f ? v : 0.f; acc[1][0] += v * wv;
            v = lv.y + rv.y; v = v > 0.f ? v : 0.f; acc[1][1] += v * wv;
            v = lv.z + rv.x; v = v > 0.f ? v : 0.f; acc[2][0] += v * wv;
            v = lv.z + rv.y; v = v > 0.f ? v : 0.f; acc[2][1] += v * wv;
            v = lv.w + rv.x; v = v > 0.f ? v : 0.f; acc[3][0] += v * wv;
            v = lv.w + rv.y; v = v > 0.f ? v : 0.f; acc[3][1] += v * wv;
        }
#pragma unroll
        for (int mi = 0; mi < 4; ++mi) {
#pragma unroll
            for (int nj = 0; nj < 2; ++nj) {
                int m = qm * 4 + mi;
                int ng = half * 32 + qn * 2 + nj;
                float val = (tL[m] + tR[ng]) - (acc[mi][nj] + bp2v);
                u64 kk = ((u64)sortable(val) << 32) | (unsigned)(m * 64 + ng);
                best = kk < best ? kk : best;
            }
        }
    }
#pragma unroll
    for (int off = 32; off > 0; off >>= 1) {
        u64 o = shfl_xor_u64(best, off);
        best = o < best ? o : best;
    }
    if (lane == 0) sred[w] = best;
    __syncthreads();
    if (t == 0) {
        u64 bb = sred[0];
        for (int p = 1; p < 4; ++p) { u64 o = sred[p]; bb = o < bb ? o : bb; }
        int idx = (int)(bb & 0xFFFFFFFFull);
        unsigned sl = subL[idx >> 6], sr = subR[idx & 63];
        outp[b * 8 + 0] = (float)((sl >> 24) & 255u);
        outp[b * 8 + 1] = (float)((sl >> 16) & 255u);
        outp[b * 8 + 2] = (float)((sl >> 8) & 255u);
        outp[b * 8 + 3] = (float)(sl & 255u);
        outp[b * 8 + 4] = (float)((sr >> 24) & 255u);
        outp[b * 8 + 5] = (float)((sr >> 16) & 255u);
        outp[b * 8 + 6] = (float)((sr >> 8) & 255u);
        outp[b * 8 + 7] = (float)(sr & 255u);
    }
}

extern "C" void kernel_launch(void* const* d_in, const int* in_sizes, int n_in,
                              void* d_out, int out_size, void* d_ws, size_t ws_size,
                              hipStream_t stream) {
    const float* pos = (const float*)d_in[0];
    const float* neg = (const float*)d_in[1];
    const int* pos_classes = (const int*)d_in[2];
    const int* target_class = (const int*)d_in[3];
    const float* Wp1 = (const float*)d_in[4];
    const float* bp1 = (const float*)d_in[5];
    const float* Wp2 = (const float*)d_in[6];
    const float* bp2 = (const float*)d_in[7];
    const float* Wu1 = (const float*)d_in[8];
    const float* bu1 = (const float*)d_in[9];
    const float* Wu2 = (const float*)d_in[10];
    const float* bu2 = (const float*)d_in[11];

    float* wsf = (float*)d_ws;
    float* HU0 = wsf;                       // 1048576
    float* HP0 = HU0 + 1048576;             // 1048576
    float* HP1 = HP0 + 1048576;             // 1048576
    float* HU1n = HP1 + 1048576;            // 524288
    float* t0 = HU1n + 524288;              // 8192
    float* sc0 = t0 + 8192;                 // 524288
    float* tA = sc0 + 524288;               // 2048
    int* pA = (int*)(tA + 2048);            // 2048
    u64* g4top = (u64*)(pA + 2048);         // 64*64 u64
    float* outp = (float*)d_out;

    g1_gemm<<<228, 256, 0, stream>>>(pos, neg, Wu1, Wp1, pos_classes,
                                     target_class, HU0, HU1n, HP0, HP1, outp);
    g2_ue_sc0<<<512, 256, 0, stream>>>(HU0, HU1n, bu1, Wu2, bu2,
                                       HP0, HP1, bp1, Wp2, bp2, t0, sc0);
    g3_top0<<<32, 1024, 0, stream>>>(sc0, t0, tA, pA);
    g4a_s1<<<32, 256, 0, stream>>>(HP0, HP1, tA, pA, bp1, Wp2, bp2, g4top);
    g4b_s2<<<8, 256, 0, stream>>>(HP0, HP1, pA, g4top, bp1, Wp2, bp2, outp);
}

// Round 9
// 209.073 us; speedup vs baseline: 1.0713x; 1.0713x over previous
//
#include <hip/hip_runtime.h>
#include <stdint.h>

#define B_ 8
#define K_ 8
#define N_ 128
#define D_ 256
#define H_ 128
#define NNEG_ 64

typedef unsigned long long u64;

// ---------------------------------------------------------------------------
// u64 wave shuffles + bitonic helpers
// ---------------------------------------------------------------------------
__device__ __forceinline__ u64 shfl_xor_u64(u64 v, int m) {
    int lo = __shfl_xor((int)(unsigned)v, m, 64);
    int hi = __shfl_xor((int)(unsigned)(v >> 32), m, 64);
    return ((u64)(unsigned)hi << 32) | (unsigned)lo;
}
__device__ __forceinline__ u64 bitonic_merge64(u64 m, int lane) {
#pragma unroll
    for (int j = 32; j > 0; j >>= 1) {
        u64 o = shfl_xor_u64(m, j);
        bool keepMin = ((lane & j) == 0);
        bool lt = m < o;
        m = (keepMin == lt) ? m : o;
    }
    return m;
}
__device__ __forceinline__ unsigned sortable(float f) {
    unsigned u = __float_as_uint(f);
    return (u & 0x80000000u) ? ~u : (u | 0x80000000u);
}
__device__ __forceinline__ float unsortable(unsigned u) {
    return __uint_as_float((u & 0x80000000u) ? (u & 0x7FFFFFFFu) : ~u);
}
// wave0-only: sort cand[0..127] ascending; 2 elems/lane
__device__ __forceinline__ void sort128_wave0(u64* cand, int cc, int lane) {
    u64 v0 = (lane < cc) ? cand[lane] : ~0ull;
    u64 v1 = (64 + lane < cc) ? cand[64 + lane] : ~0ull;
#pragma unroll
    for (int k = 2; k <= 64; k <<= 1) {
        bool d0 = ((lane & k) == 0);
        bool d1 = (k == 64) ? false : d0;
#pragma unroll
        for (int j = k >> 1; j > 0; j >>= 1) {
            u64 o0 = shfl_xor_u64(v0, j);
            bool km0 = (((lane & j) == 0) == d0);
            v0 = (km0 == (v0 < o0)) ? v0 : o0;
            u64 o1 = shfl_xor_u64(v1, j);
            bool km1 = (((lane & j) == 0) == d1);
            v1 = (km1 == (v1 < o1)) ? v1 : o1;
        }
    }
    if (v0 > v1) { u64 tmp = v0; v0 = v1; v1 = tmp; }
#pragma unroll
    for (int j = 32; j > 0; j >>= 1) {
        bool km = ((lane & j) == 0);
        u64 o0 = shfl_xor_u64(v0, j);
        v0 = (km == (v0 < o0)) ? v0 : o0;
        u64 o1 = shfl_xor_u64(v1, j);
        v1 = (km == (v1 < o1)) ? v1 : o1;
    }
    cand[lane] = v0; cand[64 + lane] = v1;
}

// ---------------------------------------------------------------------------
// g1: 4 GEMMs + is_target.  blocks 0..447 = 64x128 tiles, 4x8/thread.
// AsT[k][row] transposed (A-frag = one conflict-free b128);
// Bs column-swizzled phys = c + 4*(c>>5) -> 2-way (free) b128 reads.
// blocks 448..451 = is_target.
// ---------------------------------------------------------------------------
__global__ __launch_bounds__(256) void g1_gemm(
    const float* __restrict__ pos, const float* __restrict__ neg,
    const float* __restrict__ Wu1, const float* __restrict__ Wp1,
    const int* __restrict__ pos_classes, const int* __restrict__ target_class,
    float* __restrict__ HU0, float* __restrict__ HU1n,
    float* __restrict__ HP0, float* __restrict__ HP1,
    float* __restrict__ outp) {
    int bid = blockIdx.x;
    int t = threadIdx.x;
    if (bid >= 448) {
        int base = (bid - 448) * 2048 + t * 8;
#pragma unroll
        for (int q = 0; q < 8; ++q) {
            int idx = base + q;
            outp[64 + idx] = (pos_classes[idx] == target_class[idx >> 10]) ? 1.0f : 0.0f;
        }
        return;
    }
    const float* A; const float* W; float* OUT; int rb;
    if (bid < 128)      { A = pos; W = Wu1;           OUT = HU0;  rb = bid * 64; }
    else if (bid < 192) { A = neg; W = Wu1 + D_ * H_; OUT = HU1n; rb = (bid - 128) * 64; }
    else if (bid < 320) { A = pos; W = Wp1;           OUT = HP0;  rb = (bid - 192) * 64; }
    else                { A = pos; W = Wp1 + D_ * H_; OUT = HP1;  rb = (bid - 320) * 64; }

    __shared__ float AsT[16][68];   // [k][row]
    __shared__ float Bs[16][140];   // [k][swizzled col]
    int tx = t & 15, ty = t >> 4;
    int pb0 = tx * 8 + 4 * (tx >> 2);   // phys col of this thread's B chunk
    float acc[4][8];
#pragma unroll
    for (int i = 0; i < 4; ++i)
#pragma unroll
        for (int j = 0; j < 8; ++j) acc[i][j] = 0.f;

    for (int k0 = 0; k0 < D_; k0 += 16) {
        {
            int row = t >> 2, kq = (t & 3) * 4;
            float4 av = *(const float4*)&A[(size_t)(rb + row) * D_ + k0 + kq];
            AsT[kq + 0][row] = av.x;
            AsT[kq + 1][row] = av.y;
            AsT[kq + 2][row] = av.z;
            AsT[kq + 3][row] = av.w;
        }
#pragma unroll
        for (int i = t; i < 512; i += 256) {
            int kr = i >> 5, c4 = (i & 31) * 4;
            int ph = c4 + 4 * (c4 >> 5);
            *(float4*)&Bs[kr][ph] = *(const float4*)&W[(size_t)(k0 + kr) * H_ + c4];
        }
        __syncthreads();
#pragma unroll
        for (int kk = 0; kk < 16; ++kk) {
            float4 av = *(const float4*)&AsT[kk][ty * 4];
            float4 b0 = *(const float4*)&Bs[kk][pb0];
            float4 b1 = *(const float4*)&Bs[kk][pb0 + 4];
#pragma unroll
            for (int i = 0; i < 4; ++i) {
                float a = (&av.x)[i];
                acc[i][0] += a * b0.x;
                acc[i][1] += a * b0.y;
                acc[i][2] += a * b0.z;
                acc[i][3] += a * b0.w;
                acc[i][4] += a * b1.x;
                acc[i][5] += a * b1.y;
                acc[i][6] += a * b1.z;
                acc[i][7] += a * b1.w;
            }
        }
        __syncthreads();
    }
#pragma unroll
    for (int i = 0; i < 4; ++i) {
        int row = rb + ty * 4 + i;
        float4 o0 = {acc[i][0], acc[i][1], acc[i][2], acc[i][3]};
        float4 o1 = {acc[i][4], acc[i][5], acc[i][6], acc[i][7]};
        *(float4*)&OUT[(size_t)row * H_ + tx * 8] = o0;
        *(float4*)&OUT[(size_t)row * H_ + tx * 8 + 4] = o1;
    }
}

// ---------------------------------------------------------------------------
// g2: blocks 0..255 = ue (t0), blocks 256..511 = score0 (sc0 = dot + bp2).
// Inner loop vectorized over h (4/iter, all-b128 LDS reads).
// ---------------------------------------------------------------------------
__global__ __launch_bounds__(256) void g2_ue_sc0(
    const float* __restrict__ HU0, const float* __restrict__ HU1n,
    const float* __restrict__ bu1, const float* __restrict__ Wu2,
    const float* __restrict__ bu2v,
    const float* __restrict__ HP0, const float* __restrict__ HP1,
    const float* __restrict__ bp1, const float* __restrict__ Wp2,
    const float* __restrict__ bp2,
    float* __restrict__ t0, float* __restrict__ sc0) {
    __shared__ float Ls[32][132];
    __shared__ float Rs[64][132];
    __shared__ float wsv[128];
    __shared__ float red[32][33];

    int bid = blockIdx.x;
    int t = threadIdx.x;
    bool is_ue = bid < 256;

    if (is_ue) {
        int bk = bid >> 2, mt = bid & 3;
        for (int i = t; i < 64 * 128; i += 256) {
            int n = i >> 7, h = i & 127;
            Rs[n][h] = HU1n[(size_t)(bk * NNEG_ + n) * H_ + h];
        }
        for (int i = t; i < 32 * 128; i += 256) {
            int m = i >> 7, h = i & 127;
            Ls[m][h] = HU0[(size_t)(bk * N_ + mt * 32 + m) * H_ + h] + bu1[h];
        }
        if (t < 128) wsv[t] = Wu2[t];
    } else {
        int bid2 = bid - 256;
        int b = bid2 >> 3, m0t = (bid2 >> 1) & 3, m1t = bid2 & 1;
        const float* Lg = HP0 + (size_t)b * 2 * N_ * H_ + m0t * 32 * H_;
        const float* Rg = HP1 + (size_t)b * 2 * N_ * H_ + N_ * H_ + m1t * 64 * H_;
        for (int i = t; i < 64 * 128; i += 256) {
            int n = i >> 7, h = i & 127;
            Rs[n][h] = Rg[(size_t)n * H_ + h];
        }
        for (int i = t; i < 32 * 128; i += 256) {
            int m = i >> 7, h = i & 127;
            Ls[m][h] = Lg[(size_t)m * H_ + h] + bp1[h];
        }
        if (t < 128) wsv[t] = Wp2[t];
    }
    __syncthreads();

    int tm = t & 7, tn = t >> 3;   // m = tm + 8*i (strided), n = tn*2 + j
    float a00 = 0.f, a01 = 0.f, a10 = 0.f, a11 = 0.f;
    float a20 = 0.f, a21 = 0.f, a30 = 0.f, a31 = 0.f;
#pragma unroll 2
    for (int h = 0; h < 128; h += 4) {
        float4 wv = *(const float4*)&wsv[h];
        float4 r0 = *(const float4*)&Rs[tn * 2][h];
        float4 r1 = *(const float4*)&Rs[tn * 2 + 1][h];
        float4 l0 = *(const float4*)&Ls[tm][h];
        float4 l1 = *(const float4*)&Ls[tm + 8][h];
        float4 l2 = *(const float4*)&Ls[tm + 16][h];
        float4 l3 = *(const float4*)&Ls[tm + 24][h];
#pragma unroll
        for (int c = 0; c < 4; ++c) {
            float w = (&wv.x)[c];
            float b0 = (&r0.x)[c], b1 = (&r1.x)[c];
            float x0 = (&l0.x)[c], x1 = (&l1.x)[c];
            float x2 = (&l2.x)[c], x3 = (&l3.x)[c];
            float v;
            v = x0 + b0; v = v > 0.f ? v : 0.f; a00 += v * w;
            v = x0 + b1; v = v > 0.f ? v : 0.f; a01 += v * w;
            v = x1 + b0; v = v > 0.f ? v : 0.f; a10 += v * w;
            v = x1 + b1; v = v > 0.f ? v : 0.f; a11 += v * w;
            v = x2 + b0; v = v > 0.f ? v : 0.f; a20 += v * w;
            v = x2 + b1; v = v > 0.f ? v : 0.f; a21 += v * w;
            v = x3 + b0; v = v > 0.f ? v : 0.f; a30 += v * w;
            v = x3 + b1; v = v > 0.f ? v : 0.f; a31 += v * w;
        }
    }

    if (is_ue) {
        int bk = bid >> 2, mt = bid & 3;
        red[tm + 0][tn] = a00 + a01;
        red[tm + 8][tn] = a10 + a11;
        red[tm + 16][tn] = a20 + a21;
        red[tm + 24][tn] = a30 + a31;
        __syncthreads();
        if (t < 32) {
            float s = 0.f;
            for (int q = 0; q < 32; ++q) s += red[t][q];
            t0[bk * N_ + mt * 32 + t] = s * (1.0f / NNEG_) + bu2v[0];
        }
    } else {
        int bid2 = bid - 256;
        int b = bid2 >> 3, m0t = (bid2 >> 1) & 3, m1t = bid2 & 1;
        float bp2v = bp2[0];
        float* orow = sc0 + (size_t)b * 16384;
        float accs[4][2] = {{a00, a01}, {a10, a11}, {a20, a21}, {a30, a31}};
#pragma unroll
        for (int i = 0; i < 4; ++i) {
            int m0 = m0t * 32 + tm + 8 * i;
#pragma unroll
            for (int j = 0; j < 2; ++j) {
                int m1 = m1t * 64 + tn * 2 + j;
                orow[m0 * 128 + m1] = accs[i][j] + bp2v;
            }
        }
    }
}

// ---------------------------------------------------------------------------
// g3: level-0 top-64 per row.  32 blocks x 1024 (16 waves).
// 2-bit descent select: 16 iterations, ONE barrier each.
// ---------------------------------------------------------------------------
__global__ __launch_bounds__(1024) void g3_top0(const float* __restrict__ sc0,
                                                const float* __restrict__ t0,
                                                float* __restrict__ tA,
                                                int* __restrict__ pA) {
    int r = blockIdx.x;
    int t = threadIdx.x, lane = t & 63;
    __shared__ float tt[256];
    __shared__ unsigned cnt[16][2];
    __shared__ unsigned ccnt;
    __shared__ u64 cand[128];
    if (t < 256) tt[t] = t0[r * 256 + t];
    if (t < 32) cnt[t >> 1][t & 1] = 0u;
    if (t == 0) ccnt = 0u;
    __syncthreads();
    const float* row = sc0 + (size_t)r * 16384;
    unsigned sv[16];
#pragma unroll
    for (int j = 0; j < 16; ++j) {
        int idx = j * 1024 + t;
        float v = (tt[idx >> 7] + tt[128 + (idx & 127)]) - row[idx];
        sv[j] = sortable(v);
    }
    unsigned T = 0u;
#pragma unroll
    for (int it = 0; it < 16; ++it) {
        int p = 30 - 2 * it;
        unsigned C1 = T | (1u << p), C2 = T | (2u << p), C3 = T | (3u << p);
        unsigned c13 = 0u, c2 = 0u;
#pragma unroll
        for (int j = 0; j < 16; ++j) {
            c13 += (sv[j] < C1) ? 1u : 0u;
            c13 += (sv[j] < C3) ? 0x10000u : 0u;
            c2 += (sv[j] < C2) ? 1u : 0u;
        }
#pragma unroll
        for (int off = 32; off > 0; off >>= 1) {
            c13 += (unsigned)__shfl_xor((int)c13, off, 64);
            c2 += (unsigned)__shfl_xor((int)c2, off, 64);
        }
        if (lane == 0) { atomicAdd(&cnt[it][0], c13); atomicAdd(&cnt[it][1], c2); }
        __syncthreads();
        unsigned t13 = cnt[it][0], t2v = cnt[it][1];
        unsigned t1 = t13 & 0xFFFFu, t3 = t13 >> 16;
        unsigned k = (t3 < 64u) ? 3u : (t2v < 64u) ? 2u : (t1 < 64u) ? 1u : 0u;
        T |= (k << p);
    }
#pragma unroll
    for (int j = 0; j < 16; ++j) {
        if (sv[j] <= T) {
            unsigned pos = atomicAdd(&ccnt, 1u);
            if (pos < 128u) {
                int idx = j * 1024 + t;
                cand[pos] = ((u64)sv[j] << 32) | (unsigned)idx;
            }
        }
    }
    __syncthreads();
    if (t < 64) {
        int cc = (int)(ccnt < 128u ? ccnt : 128u);
        sort128_wave0(cand, cc, lane);
        u64 kk = cand[lane];
        int idx = (int)(kk & 0xFFFFFFFFull);
        tA[r * 64 + lane] = unsortable((unsigned)(kk >> 32));
        pA[r * 64 + lane] = ((idx >> 7) << 8) | (idx & 127);
    }
}

// ---------------------------------------------------------------------------
// g4a: level-1 scoring + per-half top-64.  32 blocks (unit u, n-half) x 256.
// ---------------------------------------------------------------------------
__global__ __launch_bounds__(256) void g4a_s1(
    const float* __restrict__ HP0, const float* __restrict__ HP1,
    const float* __restrict__ tA, const int* __restrict__ pA,
    const float* __restrict__ bp1, const float* __restrict__ Wp2,
    const float* __restrict__ bp2, u64* __restrict__ g4top) {
    int bid = blockIdx.x;
    int u = bid >> 1, half = bid & 1;
    int t = threadIdx.x, lane = t & 63, w = t >> 6;
    __shared__ float LsT[128][68];
    __shared__ float RsT[128][36];
    __shared__ float taL[64], taR[64];
    __shared__ int paL[64], paR[64];
    __shared__ float wsv[128];
    __shared__ unsigned cnt[16][2];
    __shared__ unsigned ccnt;
    __shared__ u64 cand[128];
    if (t < 64) { taL[t] = tA[(2 * u) * 64 + t]; paL[t] = pA[(2 * u) * 64 + t]; }
    else if (t < 128) { int e = t - 64; taR[e] = tA[(2 * u + 1) * 64 + e]; paR[e] = pA[(2 * u + 1) * 64 + e]; }
    if (t < 128) wsv[t] = Wp2[t];
    if (t < 32) cnt[t >> 1][t & 1] = 0u;
    if (t == 0) ccnt = 0u;
    float bp2v = bp2[0];
    __syncthreads();
    for (int i = t; i < 64 * 128; i += 256) {
        int m = i >> 7, h = i & 127;
        int pk = paL[m]; int a0 = pk >> 8, a1 = pk & 255;
        float s = HP0[(size_t)(4 * u) * 16384 + a0 * 128 + h]
                + HP0[(size_t)(4 * u + 1) * 16384 + a1 * 128 + h];
        LsT[h][m] = s * 0.5f + bp1[h];
    }
    for (int i = t; i < 32 * 128; i += 256) {
        int n = i >> 7, h = i & 127;
        int ng = half * 32 + n;
        int pk = paR[ng]; int c0 = pk >> 8, c1 = pk & 255;
        float s = HP1[(size_t)(4 * u + 2) * 16384 + c0 * 128 + h]
                + HP1[(size_t)(4 * u + 3) * 16384 + c1 * 128 + h];
        RsT[h][n] = s * 0.5f;
    }
    __syncthreads();
    int qm = w * 4 + (lane >> 4);
    int qn = lane & 15;
    float acc[4][2];
#pragma unroll
    for (int i = 0; i < 4; ++i) { acc[i][0] = 0.f; acc[i][1] = 0.f; }
#pragma unroll 2
    for (int h = 0; h < 128; ++h) {
        float4 lv = *(const float4*)&LsT[h][qm * 4];
        float2 rv = *(const float2*)&RsT[h][qn * 2];
        float wv = wsv[h];
        float v;
        v = lv.x + rv.x; v = v > 0.f ? v : 0.f; acc[0][0] += v * wv;
        v = lv.x + rv.y; v = v > 0.f ? v : 0.f; acc[0][1] += v * wv;
        v = lv.y + rv.x; v = v > 0.f ? v : 0.f; acc[1][0] += v * wv;
        v = lv.y + rv.y; v = v > 0.f ? v : 0.f; acc[1][1] += v * wv;
        v = lv.z + rv.x; v = v > 0.f ? v : 0.f; acc[2][0] += v * wv;
        v = lv.z + rv.y; v = v > 0.f ? v : 0.f; acc[2][1] += v * wv;
        v = lv.w + rv.x; v = v > 0.f ? v : 0.f; acc[3][0] += v * wv;
        v = lv.w + rv.y; v = v > 0.f ? v : 0.f; acc[3][1] += v * wv;
    }
    unsigned sv[8];
#pragma unroll
    for (int mi = 0; mi < 4; ++mi) {
#pragma unroll
        for (int nj = 0; nj < 2; ++nj) {
            int m = qm * 4 + mi;
            int ng = half * 32 + qn * 2 + nj;
            float val = (taL[m] + taR[ng]) - (acc[mi][nj] + bp2v);
            sv[mi * 2 + nj] = sortable(val);
        }
    }
    unsigned T = 0u;
#pragma unroll
    for (int it = 0; it < 16; ++it) {
        int p = 30 - 2 * it;
        unsigned C1 = T | (1u << p), C2 = T | (2u << p), C3 = T | (3u << p);
        unsigned c13 = 0u, c2 = 0u;
#pragma unroll
        for (int j = 0; j < 8; ++j) {
            c13 += (sv[j] < C1) ? 1u : 0u;
            c13 += (sv[j] < C3) ? 0x10000u : 0u;
            c2 += (sv[j] < C2) ? 1u : 0u;
        }
#pragma unroll
        for (int off = 32; off > 0; off >>= 1) {
            c13 += (unsigned)__shfl_xor((int)c13, off, 64);
            c2 += (unsigned)__shfl_xor((int)c2, off, 64);
        }
        if (lane == 0) { atomicAdd(&cnt[it][0], c13); atomicAdd(&cnt[it][1], c2); }
        __syncthreads();
        unsigned t13 = cnt[it][0], t2v = cnt[it][1];
        unsigned t1 = t13 & 0xFFFFu, t3 = t13 >> 16;
        unsigned k = (t3 < 64u) ? 3u : (t2v < 64u) ? 2u : (t1 < 64u) ? 1u : 0u;
        T |= (k << p);
    }
#pragma unroll
    for (int j = 0; j < 8; ++j) {
        if (sv[j] <= T) {
            unsigned pos = atomicAdd(&ccnt, 1u);
            if (pos < 128u) {
                int mi = j >> 1, nj = j & 1;
                int idx = (qm * 4 + mi) * 64 + half * 32 + qn * 2 + nj;
                cand[pos] = ((u64)sv[j] << 32) | (unsigned)idx;
            }
        }
    }
    __syncthreads();
    if (w == 0) {
        int cc = (int)(ccnt < 128u ? ccnt : 128u);
        sort128_wave0(cand, cc, lane);
        g4top[(size_t)bid * 64 + lane] = cand[lane];
    }
}

// ---------------------------------------------------------------------------
// g4b: merge half-topks -> level-1 top-64; level-2 scoring (S=4) + argmin; out.
// ---------------------------------------------------------------------------
__global__ __launch_bounds__(256) void g4b_s2(
    const float* __restrict__ HP0, const float* __restrict__ HP1,
    const int* __restrict__ pA, const u64* __restrict__ g4top,
    const float* __restrict__ bp1, const float* __restrict__ Wp2,
    const float* __restrict__ bp2, float* __restrict__ outp) {
    int b = blockIdx.x;
    int t = threadIdx.x, lane = t & 63, w = t >> 6;
    __shared__ float LsT[128][68];
    __shared__ float RsT[128][36];
    __shared__ float tL[64], tR[64];
    __shared__ unsigned subL[64], subR[64];
    __shared__ float wsv[128];
    __shared__ u64 sred[4];
    if (t < 128) wsv[t] = Wp2[t];
    float bp2v = bp2[0];
    if (w < 2) {
        const u64* A = g4top + (size_t)(4 * b + 2 * w) * 64;
        const u64* Bp = g4top + (size_t)(4 * b + 2 * w + 1) * 64;
        u64 x = A[lane], y = Bp[63 - lane];
        u64 m = x < y ? x : y;
        m = bitonic_merge64(m, lane);
        int idx = (int)(m & 0xFFFFFFFFull);
        int p0 = idx >> 6, p1 = idx & 63;
        float val = unsortable((unsigned)(m >> 32));
        int rowL = 4 * b + 2 * w;
        int pkL = pA[rowL * 64 + p0];
        int pkR = pA[(rowL + 1) * 64 + p1];
        unsigned leaves = ((unsigned)pkL << 16) | (unsigned)pkR;
        if (w == 0) { tL[lane] = val; subL[lane] = leaves; }
        else        { tR[lane] = val; subR[lane] = leaves; }
    }
    __syncthreads();
    for (int i = t; i < 64 * 128; i += 256) {
        int m = i >> 7, h = i & 127;
        unsigned s4 = subL[m];
        float s = HP0[(size_t)(8 * b + 0) * 16384 + ((s4 >> 24) & 255u) * 128 + h]
                + HP0[(size_t)(8 * b + 1) * 16384 + ((s4 >> 16) & 255u) * 128 + h]
                + HP0[(size_t)(8 * b + 2) * 16384 + ((s4 >> 8) & 255u) * 128 + h]
                + HP0[(size_t)(8 * b + 3) * 16384 + (s4 & 255u) * 128 + h];
        LsT[h][m] = s * 0.25f + bp1[h];
    }
    u64 best = ~0ull;
    int qm = w * 4 + (lane >> 4);
    int qn = lane & 15;
    for (int half = 0; half < 2; ++half) {
        __syncthreads();
        for (int i = t; i < 32 * 128; i += 256) {
            int n = i >> 7, h = i & 127;
            int ng = half * 32 + n;
            unsigned s4 = subR[ng];
            float s = HP1[(size_t)(8 * b + 4) * 16384 + ((s4 >> 24) & 255u) * 128 + h]
                    + HP1[(size_t)(8 * b + 5) * 16384 + ((s4 >> 16) & 255u) * 128 + h]
                    + HP1[(size_t)(8 * b + 6) * 16384 + ((s4 >> 8) & 255u) * 128 + h]
                    + HP1[(size_t)(8 * b + 7) * 16384 + (s4 & 255u) * 128 + h];
            RsT[h][n] = s * 0.25f;
        }
        __syncthreads();
        float acc[4][2];
#pragma unroll
        for (int i = 0; i < 4; ++i) { acc[i][0] = 0.f; acc[i][1] = 0.f; }
#pragma unroll 2
        for (int h = 0; h < 128; ++h) {
            float4 lv = *(const float4*)&LsT[h][qm * 4];
            float2 rv = *(const float2*)&RsT[h][qn * 2];
            float wv = wsv[h];
            float v;
            v = lv.x + rv.x; v = v > 0.f ? v : 0.f; acc[0][0] += v * wv;
            v = lv.x + rv.y; v = v > 0.f ? v : 0.f; acc[0][1] += v * wv;
            v = lv.y + rv.x; v = v > 0.f ? v : 0.f; acc[1][0] += v * wv;
            v = lv.y + rv.y; v = v > 0.f ? v : 0.f; acc[1][1] += v * wv;
            v = lv.z + rv.x; v = v > 0.f ? v : 0.f; acc[2][0] += v * wv;
            v = lv.z + rv.y; v = v > 0.f ? v : 0.f; acc[2][1] += v * wv;
            v = lv.w + rv.x; v = v > 0.f ? v : 0.f; acc[3][0] += v * wv;
            v = lv.w + rv.y; v = v > 0.f ? v : 0.f; acc[3][1] += v * wv;
        }
#pragma unroll
        for (int mi = 0; mi < 4; ++mi) {
#pragma unroll
            for (int nj = 0; nj < 2; ++nj) {
                int m = qm * 4 + mi;
                int ng = half * 32 + qn * 2 + nj;
                float val = (tL[m] + tR[ng]) - (acc[mi][nj] + bp2v);
                u64 kk = ((u64)sortable(val) << 32) | (unsigned)(m * 64 + ng);
                best = kk < best ? kk : best;
            }
        }
    }
#pragma unroll
    for (int off = 32; off > 0; off >>= 1) {
        u64 o = shfl_xor_u64(best, off);
        best = o < best ? o : best;
    }
    if (lane == 0) sred[w] = best;
    __syncthreads();
    if (t == 0) {
        u64 bb = sred[0];
        for (int p = 1; p < 4; ++p) { u64 o = sred[p]; bb = o < bb ? o : bb; }
        int idx = (int)(bb & 0xFFFFFFFFull);
        unsigned sl = subL[idx >> 6], sr = subR[idx & 63];
        outp[b * 8 + 0] = (float)((sl >> 24) & 255u);
        outp[b * 8 + 1] = (float)((sl >> 16) & 255u);
        outp[b * 8 + 2] = (float)((sl >> 8) & 255u);
        outp[b * 8 + 3] = (float)(sl & 255u);
        outp[b * 8 + 4] = (float)((sr >> 24) & 255u);
        outp[b * 8 + 5] = (float)((sr >> 16) & 255u);
        outp[b * 8 + 6] = (float)((sr >> 8) & 255u);
        outp[b * 8 + 7] = (float)(sr & 255u);
    }
}

extern "C" void kernel_launch(void* const* d_in, const int* in_sizes, int n_in,
                              void* d_out, int out_size, void* d_ws, size_t ws_size,
                              hipStream_t stream) {
    const float* pos = (const float*)d_in[0];
    const float* neg = (const float*)d_in[1];
    const int* pos_classes = (const int*)d_in[2];
    const int* target_class = (const int*)d_in[3];
    const float* Wp1 = (const float*)d_in[4];
    const float* bp1 = (const float*)d_in[5];
    const float* Wp2 = (const float*)d_in[6];
    const float* bp2 = (const float*)d_in[7];
    const float* Wu1 = (const float*)d_in[8];
    const float* bu1 = (const float*)d_in[9];
    const float* Wu2 = (const float*)d_in[10];
    const float* bu2 = (const float*)d_in[11];

    float* wsf = (float*)d_ws;
    float* HU0 = wsf;                       // 1048576
    float* HP0 = HU0 + 1048576;             // 1048576
    float* HP1 = HP0 + 1048576;             // 1048576
    float* HU1n = HP1 + 1048576;            // 524288
    float* t0 = HU1n + 524288;              // 8192
    float* sc0 = t0 + 8192;                 // 524288
    float* tA = sc0 + 524288;               // 2048
    int* pA = (int*)(tA + 2048);            // 2048
    u64* g4top = (u64*)(pA + 2048);         // 64*64 u64
    float* outp = (float*)d_out;

    g1_gemm<<<452, 256, 0, stream>>>(pos, neg, Wu1, Wp1, pos_classes,
                                     target_class, HU0, HU1n, HP0, HP1, outp);
    g2_ue_sc0<<<512, 256, 0, stream>>>(HU0, HU1n, bu1, Wu2, bu2,
                                       HP0, HP1, bp1, Wp2, bp2, t0, sc0);
    g3_top0<<<32, 1024, 0, stream>>>(sc0, t0, tA, pA);
    g4a_s1<<<32, 256, 0, stream>>>(HP0, HP1, tA, pA, bp1, Wp2, bp2, g4top);
    g4b_s2<<<8, 256, 0, stream>>>(HP0, HP1, pA, g4top, bp1, Wp2, bp2, outp);
}